// Round 1
// baseline (25.810 us; speedup 1.0000x reference)
//
#include <hip/hip_runtime.h>

// out[b,s,:] = vocab_weight[idx[b,s]] + pos_weight[s] + tokentype_weight[types[b,s]]
// B=8, S=2048, H=1024, fp32 everywhere. Memory-bound gather+add.

#define HIDDEN 1024
#define SEQ 2048

__global__ __launch_bounds__(256) void embed_fused_kernel(
    const int* __restrict__ idx,
    const int* __restrict__ types,
    const float* __restrict__ vocab_w,
    const float* __restrict__ pos_w,
    const float* __restrict__ tt_w,
    float* __restrict__ out)
{
    const int token = blockIdx.x;           // 0 .. B*S-1, one block per token row
    const int s     = token & (SEQ - 1);    // position within sequence
    const int row   = idx[token];           // vocab row (wave-uniform per block)
    const int tt    = types[token];         // tokentype row (wave-uniform)
    const int t     = threadIdx.x;          // 0..255, one float4 each (1024 floats/row)

    const float4* v = reinterpret_cast<const float4*>(vocab_w + (size_t)row * HIDDEN);
    const float4* p = reinterpret_cast<const float4*>(pos_w   + (size_t)s   * HIDDEN);
    const float4* q = reinterpret_cast<const float4*>(tt_w    + (size_t)tt  * HIDDEN);
    float4*       o = reinterpret_cast<float4*>(out + (size_t)token * HIDDEN);

    float4 a = v[t];
    float4 b = p[t];
    float4 c = q[t];
    o[t] = make_float4(a.x + b.x + c.x,
                       a.y + b.y + c.y,
                       a.z + b.z + c.z,
                       a.w + b.w + c.w);
}

extern "C" void kernel_launch(void* const* d_in, const int* in_sizes, int n_in,
                              void* d_out, int out_size, void* d_ws, size_t ws_size,
                              hipStream_t stream)
{
    const int*   idx     = (const int*)d_in[0];   // [B,S] int32
    const int*   types   = (const int*)d_in[1];   // [B,S] int32
    const float* vocab_w = (const float*)d_in[2]; // [VOCAB, H] fp32
    const float* pos_w   = (const float*)d_in[3]; // [S, H] fp32
    const float* tt_w    = (const float*)d_in[4]; // [NUM_TT, H] fp32
    float*       out     = (float*)d_out;         // [B,S,H] fp32

    const int n_tokens = in_sizes[0];             // B*S = 16384
    embed_fused_kernel<<<n_tokens, 256, 0, stream>>>(idx, types, vocab_w, pos_w, tt_w, out);
}